// Round 3
// baseline (170.688 us; speedup 1.0000x reference)
//
#include <hip/hip_runtime.h>
#include <stdint.h>
#include <stddef.h>

#define B_TOT   16384
#define NUM_IN  256
#define N_NODES 1024
#define NN      768
#define K       8
#define NUM_OUT 64
#define NB      64      // batch elements per block (= lanes)
#define MAXL    800     // max levels we can represent (true max = 768)

// 64-byte schedule record, one per non-input node, sorted by dependency level.
// P[k] = swizzled LDS element base for pred k: idx*64 + ((idx&31)<<1)
// lane's element index is then P ^ lane (one VALU op in the hot loop).
struct Rec {
  uint32_t p01, p23, p45, p67;   // P[8] packed as u16 pairs
  uint32_t outPh;                // swizzled base of the output node (low 16)
  float    w[8];                 // edge_w * response (response folded in)
  float    bias;
  uint32_t pad0, pad1;
};
static_assert(sizeof(Rec) == 64, "Rec must be 64B");

// ---------------------------------------------------------------------------
// Setup: compute exact dependency levels (parallel Bellman-Ford, converges in
// ~graph-depth iterations), counting-sort nodes by level, emit packed records.
// Single block, 768 threads (thread t owns node 256+t). ~few microseconds.
// ---------------------------------------------------------------------------
__global__ __launch_bounds__(NN)
void setup_kernel(const int* __restrict__ in_idx,
                  const float* __restrict__ edge_w,
                  const float* __restrict__ bias,
                  const float* __restrict__ response,
                  const int* __restrict__ out_idx,
                  int* __restrict__ g_nlev,
                  int* __restrict__ g_loff,
                  Rec* __restrict__ recs)
{
  __shared__ int      lvl[N_NODES];
  __shared__ uint16_t pidx[NN][K];
  __shared__ int      hist[MAXL];
  __shared__ int      cnt[MAXL];
  __shared__ int      offs[MAXL + 2];
  __shared__ int      changed;
  __shared__ int      maxlv;

  const int t = threadIdx.x;

  for (int i = t; i < N_NODES; i += NN) lvl[i] = 0;
  for (int i = t; i < MAXL; i += NN) { hist[i] = 0; cnt[i] = 0; }
  if (t == 0) maxlv = 0;

  int idxs[K];
#pragma unroll
  for (int k = 0; k < K; ++k) {
    int id = in_idx[t * K + k];        // deg == K for all nodes here (node>=256)
    idxs[k] = id;
    pidx[t][k] = (uint16_t)id;
  }
  __syncthreads();

  // Bellman-Ford to fixed point: lvl[n] = 1 + max(lvl[preds]); inputs stay 0.
  for (int iter = 0; iter < 800; ++iter) {
    int nl = 0;
#pragma unroll
    for (int k = 0; k < K; ++k) {
      int l = lvl[pidx[t][k]];
      nl = (l > nl) ? l : nl;
    }
    nl += 1;
    __syncthreads();                 // all reads done
    if (t == 0) changed = 0;
    int cur = lvl[NUM_IN + t];       // only owner writes this entry
    __syncthreads();                 // changed=0 visible
    if (nl != cur) { lvl[NUM_IN + t] = nl; changed = 1; }
    __syncthreads();
    if (changed == 0) break;         // uniform exit
  }

  const int L = lvl[NUM_IN + t];     // >= 1
  atomicAdd(&hist[L], 1);
  atomicMax(&maxlv, L);
  __syncthreads();
  const int ml = maxlv;
  if (t == 0) {
    offs[1] = 0;
    for (int l = 1; l <= ml; ++l) offs[l + 1] = offs[l] + hist[l];
  }
  __syncthreads();
  const int pos = offs[L] + atomicAdd(&cnt[L], 1);

  // Build the packed record.
  uint32_t P[K];
#pragma unroll
  for (int k = 0; k < K; ++k) {
    uint32_t id = (uint32_t)idxs[k];
    P[k] = id * 64u + ((id & 31u) << 1);
  }
  Rec r;
  r.p01 = P[0] | (P[1] << 16);
  r.p23 = P[2] | (P[3] << 16);
  r.p45 = P[4] | (P[5] << 16);
  r.p67 = P[6] | (P[7] << 16);
  uint32_t oid = (uint32_t)out_idx[t];
  r.outPh = oid * 64u + ((oid & 31u) << 1);
  const float rsp = response[t];
#pragma unroll
  for (int k = 0; k < K; ++k) r.w[k] = edge_w[t * K + k] * rsp;
  r.bias = bias[t];
  r.pad0 = 0; r.pad1 = 0;
  recs[pos] = r;

  if (t <= ml) g_loff[t] = offs[t + 1];   // g_loff[i] = start of level i+1; g_loff[ml] = NN
  if (t == 0)  g_nlev[0] = ml;
}

// ---------------------------------------------------------------------------
// Eval: one block per 64 batch elements (lane = batch element). Node values in
// 128 KiB LDS (fp16), XOR-swizzled so both the staging writes and the level
// loop gathers are bank-conflict-free. 4 waves split each level's nodes.
// ---------------------------------------------------------------------------
__global__ __launch_bounds__(256)
void eval_kernel(const float* __restrict__ inputs,
                 const int* __restrict__ output_idx,
                 const int* __restrict__ g_nlev,
                 const int* __restrict__ g_loff,
                 const Rec* __restrict__ recs,
                 float* __restrict__ out)
{
  __shared__ _Float16 vals[N_NODES * NB];   // 128 KiB
  __shared__ int      loffs[MAXL + 1];

  const uint32_t tid  = threadIdx.x;
  const uint32_t lane = tid & 63u;
  const uint32_t wave = tid >> 6;
  const int      base = blockIdx.x * NB;

  const int nlev = g_nlev[0];
  for (int i = (int)tid; i <= nlev; i += 256) loffs[i] = g_loff[i];

  // Stage 64 rows x 256 input cols: coalesced global reads, swizzled LDS writes.
  const uint32_t swz = tid * 64u + ((tid & 31u) << 1);   // tid == input node id
  for (int c = 0; c < NB; ++c) {
    float v = inputs[(size_t)(base + c) * NUM_IN + tid];
    vals[swz ^ (uint32_t)c] = (_Float16)v;
  }
  __syncthreads();

  for (int l = 0; l < nlev; ++l) {
    const int beg = loffs[l], end = loffs[l + 1];
    for (int j = beg + (int)wave; j < end; j += 4) {
      const int js = __builtin_amdgcn_readfirstlane(j);   // force SGPR addressing
      const Rec rr = recs[js];
      const uint32_t P0 = rr.p01 & 0xFFFFu, P1 = rr.p01 >> 16;
      const uint32_t P2 = rr.p23 & 0xFFFFu, P3 = rr.p23 >> 16;
      const uint32_t P4 = rr.p45 & 0xFFFFu, P5 = rr.p45 >> 16;
      const uint32_t P6 = rr.p67 & 0xFFFFu, P7 = rr.p67 >> 16;

      float v0 = (float)vals[P0 ^ lane];
      float v1 = (float)vals[P1 ^ lane];
      float v2 = (float)vals[P2 ^ lane];
      float v3 = (float)vals[P3 ^ lane];
      float v4 = (float)vals[P4 ^ lane];
      float v5 = (float)vals[P5 ^ lane];
      float v6 = (float)vals[P6 ^ lane];
      float v7 = (float)vals[P7 ^ lane];

      float s0 = __builtin_fmaf(rr.w[0], v0, rr.bias);
      float s1 = rr.w[1] * v1;
      float s2 = rr.w[2] * v2;
      float s3 = rr.w[3] * v3;
      s0 = __builtin_fmaf(rr.w[4], v4, s0);
      s1 = __builtin_fmaf(rr.w[5], v5, s1);
      s2 = __builtin_fmaf(rr.w[6], v6, s2);
      s3 = __builtin_fmaf(rr.w[7], v7, s3);
      const float x = (s0 + s1) + (s2 + s3);

      // tanh(x) = 1 - 2/(exp(2x)+1); saturates correctly at +-inf.
      const float e  = __expf(x + x);
      const float rc = __builtin_amdgcn_rcpf(e + 1.0f);
      const float y  = __builtin_fmaf(-2.0f, rc, 1.0f);

      vals[(rr.outPh & 0xFFFFu) ^ lane] = (_Float16)y;
    }
    __syncthreads();
  }

  // Emit outputs: out[(base+b)*64 + j], lane = j (coalesced 256B/wave stores).
  const uint32_t oid  = (uint32_t)output_idx[lane];
  const uint32_t oswz = oid * 64u + ((oid & 31u) << 1);
  for (int c = 0; c < 16; ++c) {
    const uint32_t b = wave + (uint32_t)c * 4u;
    float v = (float)vals[oswz ^ b];
    out[(size_t)(base + b) * NUM_OUT + lane] = v;
  }
}

// ---------------------------------------------------------------------------
extern "C" void kernel_launch(void* const* d_in, const int* in_sizes, int n_in,
                              void* d_out, int out_size, void* d_ws, size_t ws_size,
                              hipStream_t stream)
{
  (void)in_sizes; (void)n_in; (void)out_size; (void)ws_size;

  const float* inputs     = (const float*)d_in[0];
  const float* edge_w     = (const float*)d_in[1];
  const float* bias       = (const float*)d_in[2];
  const float* response   = (const float*)d_in[3];
  const int*   in_idx     = (const int*)d_in[4];
  // d_in[5] = edge_mask: all-true for this graph (deg = min(K, node) = K since
  // every non-input node id >= 256 > K), so it is ignored.
  const int*   out_idx    = (const int*)d_in[6];
  const int*   output_idx = (const int*)d_in[7];
  float*       out        = (float*)d_out;

  char* ws = (char*)d_ws;
  int* g_nlev = (int*)ws;                 // 1 int
  int* g_loff = (int*)(ws + 256);         // up to 800 ints
  Rec* recs   = (Rec*)(ws + 8192);        // 768 * 64B = 48 KiB

  hipLaunchKernelGGL(setup_kernel, dim3(1), dim3(NN), 0, stream,
                     in_idx, edge_w, bias, response, out_idx,
                     g_nlev, g_loff, recs);
  hipLaunchKernelGGL(eval_kernel, dim3(B_TOT / NB), dim3(256), 0, stream,
                     inputs, output_idx, g_nlev, g_loff, recs, out);
}

// Round 7
// 136.106 us; speedup vs baseline: 1.2541x; 1.2541x over previous
//
#include <hip/hip_runtime.h>
#include <stdint.h>
#include <stddef.h>

#define B_TOT   16384
#define NUM_IN  256
#define N_NODES 1024
#define NN      768
#define K       8
#define NUM_OUT 64
#define NB      64      // batch elements per block (= lanes)
#define MAXL    800     // max levels we can represent (true max = 768)
#define TPB     768     // eval threads per block (12 waves, 3/SIMD)
#define WPB     12      // waves per eval block

// 64-byte schedule record, one per non-input node, sorted by dependency level.
// P[k] = swizzled LDS element base for pred k: idx*64 + ((idx&31)<<1)
// lane's element index is then P ^ lane (one VALU op in the hot loop).
struct Rec {
  uint32_t p01, p23, p45, p67;   // P[8] packed as u16 pairs
  uint32_t outPh;                // swizzled base of the output node (low 16)
  float    w[8];                 // edge_w * response (response folded in)
  float    bias;
  uint32_t pad0, pad1;
};
static_assert(sizeof(Rec) == 64, "Rec must be 64B");

// ---------------------------------------------------------------------------
// Setup: exact dependency levels via in-place Bellman-Ford with the R3
// 3-barrier owner-writes protocol (HW-validated race-free in Round 3; the
// 1-barrier ping-pong variant raced on the flag slot and corrupted replays).
// Then counting-sort by level and emit packed records.
// ---------------------------------------------------------------------------
__global__ __launch_bounds__(NN)
void setup_kernel(const int* __restrict__ in_idx,
                  const float* __restrict__ edge_w,
                  const float* __restrict__ bias,
                  const float* __restrict__ response,
                  const int* __restrict__ out_idx,
                  int* __restrict__ g_nlev,
                  int* __restrict__ g_loff,
                  Rec* __restrict__ recs)
{
  __shared__ int lvl[N_NODES];
  __shared__ int hist[MAXL];
  __shared__ int cnt[MAXL];
  __shared__ int offs[MAXL + 2];
  __shared__ int changed;
  __shared__ int maxlv;

  const int t = threadIdx.x;

  for (int i = t; i < N_NODES; i += NN) lvl[i] = 0;
  for (int i = t; i < MAXL; i += NN) { hist[i] = 0; cnt[i] = 0; }
  if (t == 0) maxlv = 0;

  int idxs[K];
#pragma unroll
  for (int k = 0; k < K; ++k)
    idxs[k] = in_idx[t * K + k];       // deg == K for all nodes (node id >= 256)
  __syncthreads();

  // Bellman-Ford to fixed point: lvl[n] = 1 + max(lvl[preds]); inputs stay 0.
  // Race-freedom: `changed` is read only after barrier 3; t0's reset happens
  // after barrier 1 of the NEXT iteration, which all threads reach only after
  // their read. Owner-writes (thread t owns lvl[NUM_IN+t]).
  for (int iter = 0; iter < 800; ++iter) {
    int nl = 0;
#pragma unroll
    for (int k = 0; k < K; ++k) {
      int l = lvl[idxs[k]];
      nl = (l > nl) ? l : nl;
    }
    nl += 1;
    __syncthreads();                 // (1) all reads done
    if (t == 0) changed = 0;
    int cur = lvl[NUM_IN + t];
    __syncthreads();                 // (2) changed=0 visible
    if (nl != cur) { lvl[NUM_IN + t] = nl; changed = 1; }
    __syncthreads();                 // (3) writes + flag final
    if (changed == 0) break;         // uniform exit
  }

  const int L = lvl[NUM_IN + t];     // >= 1
  atomicAdd(&hist[L], 1);
  atomicMax(&maxlv, L);
  __syncthreads();
  const int ml = maxlv;
  if (t == 0) {
    offs[1] = 0;
    for (int l = 1; l <= ml; ++l) offs[l + 1] = offs[l] + hist[l];
  }
  __syncthreads();
  const int pos = offs[L] + atomicAdd(&cnt[L], 1);

  // Build the packed record.
  uint32_t P[K];
#pragma unroll
  for (int k = 0; k < K; ++k) {
    uint32_t id = (uint32_t)idxs[k];
    P[k] = id * 64u + ((id & 31u) << 1);
  }
  Rec r;
  r.p01 = P[0] | (P[1] << 16);
  r.p23 = P[2] | (P[3] << 16);
  r.p45 = P[4] | (P[5] << 16);
  r.p67 = P[6] | (P[7] << 16);
  uint32_t oid = (uint32_t)out_idx[t];
  r.outPh = oid * 64u + ((oid & 31u) << 1);
  const float rsp = response[t];
#pragma unroll
  for (int k = 0; k < K; ++k) r.w[k] = edge_w[t * K + k] * rsp;
  r.bias = bias[t];
  r.pad0 = 0; r.pad1 = 0;
  recs[pos] = r;

  if (t <= ml) g_loff[t] = offs[t + 1];   // g_loff[i] = start of level i+1; g_loff[ml] = NN
  if (t == 0)  g_nlev[0] = ml;
}

// ---------------------------------------------------------------------------
// Eval: one block per 64 batch elements (lane = batch element). Node values in
// 128 KiB LDS (fp16), XOR-swizzled (verified 0 bank conflicts in R3). 12 waves
// (3/SIMD) split each level's nodes; records prefetched one iter ahead (SGPRs).
// ---------------------------------------------------------------------------
__global__ __launch_bounds__(TPB, 3)
void eval_kernel(const float* __restrict__ inputs,
                 const int* __restrict__ output_idx,
                 const int* __restrict__ g_nlev,
                 const int* __restrict__ g_loff,
                 const Rec* __restrict__ recs,
                 float* __restrict__ out)
{
  __shared__ _Float16 vals[N_NODES * NB];   // 128 KiB
  __shared__ int      loffs[MAXL + 1];

  const uint32_t tid  = threadIdx.x;
  const uint32_t lane = tid & 63u;
  const uint32_t wave = tid >> 6;           // 0..11
  const int      base = blockIdx.x * NB;

  const int nlev = g_nlev[0];
  for (int i = (int)tid; i <= nlev; i += TPB) loffs[i] = g_loff[i];

  // Stage 64 rows x 256 input cols: thread -> (col = tid&255, c-group = tid>>8).
  // Coalesced global reads (256 consecutive threads per c), swizzled LDS writes.
  const uint32_t col = tid & 255u;
  const uint32_t cg  = tid >> 8;            // 0..2
  const uint32_t swz = col * 64u + ((col & 31u) << 1);
  for (uint32_t c = cg; c < NB; c += 3) {
    float v = inputs[(size_t)(base + c) * NUM_IN + col];
    vals[swz ^ c] = (_Float16)v;
  }
  __syncthreads();

  for (int l = 0; l < nlev; ++l) {
    const int beg = loffs[l], end = loffs[l + 1];
    int j = beg + (int)wave;
    if (j < end) {
      Rec rr = recs[__builtin_amdgcn_readfirstlane(j)];
      for (;;) {
        // Prefetch next record (wave-uniform addr -> SGPRs) before the math.
        const int jn = j + WPB;
        const bool has = jn < end;
        Rec rn;
        if (has) rn = recs[__builtin_amdgcn_readfirstlane(jn)];

        const uint32_t P0 = rr.p01 & 0xFFFFu, P1 = rr.p01 >> 16;
        const uint32_t P2 = rr.p23 & 0xFFFFu, P3 = rr.p23 >> 16;
        const uint32_t P4 = rr.p45 & 0xFFFFu, P5 = rr.p45 >> 16;
        const uint32_t P6 = rr.p67 & 0xFFFFu, P7 = rr.p67 >> 16;

        float v0 = (float)vals[P0 ^ lane];
        float v1 = (float)vals[P1 ^ lane];
        float v2 = (float)vals[P2 ^ lane];
        float v3 = (float)vals[P3 ^ lane];
        float v4 = (float)vals[P4 ^ lane];
        float v5 = (float)vals[P5 ^ lane];
        float v6 = (float)vals[P6 ^ lane];
        float v7 = (float)vals[P7 ^ lane];

        float s0 = __builtin_fmaf(rr.w[0], v0, rr.bias);
        float s1 = rr.w[1] * v1;
        float s2 = rr.w[2] * v2;
        float s3 = rr.w[3] * v3;
        s0 = __builtin_fmaf(rr.w[4], v4, s0);
        s1 = __builtin_fmaf(rr.w[5], v5, s1);
        s2 = __builtin_fmaf(rr.w[6], v6, s2);
        s3 = __builtin_fmaf(rr.w[7], v7, s3);
        const float x = (s0 + s1) + (s2 + s3);

        // tanh(x) = 1 - 2/(exp(2x)+1); saturates correctly at +-inf.
        const float e  = __expf(x + x);
        const float rc = __builtin_amdgcn_rcpf(e + 1.0f);
        const float y  = __builtin_fmaf(-2.0f, rc, 1.0f);

        vals[(rr.outPh & 0xFFFFu) ^ lane] = (_Float16)y;

        if (!has) break;
        rr = rn; j = jn;
      }
    }
    __syncthreads();
  }

  // Emit outputs: out[(base+b)*64 + lane] (coalesced 256B/wave stores).
  const uint32_t oid  = (uint32_t)output_idx[lane];
  const uint32_t oswz = oid * 64u + ((oid & 31u) << 1);
  for (uint32_t k = 0; k < 6; ++k) {
    const uint32_t b = wave + k * 12u;
    if (b < NB) {
      float v = (float)vals[oswz ^ b];
      out[(size_t)(base + b) * NUM_OUT + lane] = v;
    }
  }
}

// ---------------------------------------------------------------------------
extern "C" void kernel_launch(void* const* d_in, const int* in_sizes, int n_in,
                              void* d_out, int out_size, void* d_ws, size_t ws_size,
                              hipStream_t stream)
{
  (void)in_sizes; (void)n_in; (void)out_size; (void)ws_size;

  const float* inputs     = (const float*)d_in[0];
  const float* edge_w     = (const float*)d_in[1];
  const float* bias       = (const float*)d_in[2];
  const float* response   = (const float*)d_in[3];
  const int*   in_idx     = (const int*)d_in[4];
  // d_in[5] = edge_mask: all-true for this graph (deg = min(K, node) = K since
  // every non-input node id >= 256 > K), so it is ignored.
  const int*   out_idx    = (const int*)d_in[6];
  const int*   output_idx = (const int*)d_in[7];
  float*       out        = (float*)d_out;

  char* ws = (char*)d_ws;
  int* g_nlev = (int*)ws;                 // 1 int
  int* g_loff = (int*)(ws + 256);         // up to 800 ints
  Rec* recs   = (Rec*)(ws + 8192);        // 768 * 64B = 48 KiB

  hipLaunchKernelGGL(setup_kernel, dim3(1), dim3(NN), 0, stream,
                     in_idx, edge_w, bias, response, out_idx,
                     g_nlev, g_loff, recs);
  hipLaunchKernelGGL(eval_kernel, dim3(B_TOT / NB), dim3(TPB), 0, stream,
                     inputs, output_idx, g_nlev, g_loff, recs, out);
}

// Round 9
// 128.282 us; speedup vs baseline: 1.3306x; 1.0610x over previous
//
#include <hip/hip_runtime.h>
#include <stdint.h>
#include <stddef.h>

#define B_TOT   16384
#define NUM_IN  256
#define N_NODES 1024
#define NN      768
#define K       8
#define NUM_OUT 64
#define NB      64      // batch elements per block (= lanes)
#define MAXL    800     // max levels we can represent (true max = 768)
#define TPB     1024    // eval threads per block (16 waves, 4/SIMD)
#define WPB     16      // waves per eval block

typedef _Float16 h2 __attribute__((ext_vector_type(2)));

// 64-byte schedule record, one per non-input node, sorted by dependency level.
// p[k] = swizzled LDS ELEMENT index base for pred k: id*64 + ((id&31)<<1);
// lane's element is p[k] ^ lane. Weights are fp16 pairs (response folded in).
struct Rec {
  uint32_t p[8];                 // unpacked swizzled element bases
  uint32_t w01, w23, w45, w67;   // fp16x2 packed weights
  uint32_t outPh;                // swizzled element base of the output node
  float    bias;
  uint32_t pad0, pad1;
};
static_assert(sizeof(Rec) == 64, "Rec must be 64B");

// ---------------------------------------------------------------------------
// Setup: exact dependency levels via in-place Bellman-Ford with the R3
// 3-barrier owner-writes protocol (HW-validated race-free across graph
// replays in R3/R7). Then counting-sort by level and emit packed records.
// ---------------------------------------------------------------------------
__global__ __launch_bounds__(NN)
void setup_kernel(const int* __restrict__ in_idx,
                  const float* __restrict__ edge_w,
                  const float* __restrict__ bias,
                  const float* __restrict__ response,
                  const int* __restrict__ out_idx,
                  int* __restrict__ g_nlev,
                  int* __restrict__ g_loff,
                  Rec* __restrict__ recs)
{
  __shared__ int lvl[N_NODES];
  __shared__ int hist[MAXL];
  __shared__ int cnt[MAXL];
  __shared__ int offs[MAXL + 2];
  __shared__ int changed;
  __shared__ int maxlv;

  const int t = threadIdx.x;

  for (int i = t; i < N_NODES; i += NN) lvl[i] = 0;
  for (int i = t; i < MAXL; i += NN) { hist[i] = 0; cnt[i] = 0; }
  if (t == 0) maxlv = 0;

  int idxs[K];
#pragma unroll
  for (int k = 0; k < K; ++k)
    idxs[k] = in_idx[t * K + k];       // deg == K for all nodes (node id >= 256)
  __syncthreads();

  // Bellman-Ford to fixed point: lvl[n] = 1 + max(lvl[preds]); inputs stay 0.
  // Race-freedom: `changed` is read only after barrier 3; t0's reset happens
  // after barrier 1 of the NEXT iteration. Owner-writes.
  for (int iter = 0; iter < 800; ++iter) {
    int nl = 0;
#pragma unroll
    for (int k = 0; k < K; ++k) {
      int l = lvl[idxs[k]];
      nl = (l > nl) ? l : nl;
    }
    nl += 1;
    __syncthreads();                 // (1) all reads done
    if (t == 0) changed = 0;
    int cur = lvl[NUM_IN + t];
    __syncthreads();                 // (2) changed=0 visible
    if (nl != cur) { lvl[NUM_IN + t] = nl; changed = 1; }
    __syncthreads();                 // (3) writes + flag final
    if (changed == 0) break;         // uniform exit
  }

  const int L = lvl[NUM_IN + t];     // >= 1
  atomicAdd(&hist[L], 1);
  atomicMax(&maxlv, L);
  __syncthreads();
  const int ml = maxlv;
  if (t == 0) {
    offs[1] = 0;
    for (int l = 1; l <= ml; ++l) offs[l + 1] = offs[l] + hist[l];
  }
  __syncthreads();
  const int pos = offs[L] + atomicAdd(&cnt[L], 1);

  // Build the packed record.
  Rec r;
#pragma unroll
  for (int k = 0; k < K; ++k) {
    uint32_t id = (uint32_t)idxs[k];
    r.p[k] = id * 64u + ((id & 31u) << 1);
  }
  const float rsp = response[t];
  uint16_t hw[K];
#pragma unroll
  for (int k = 0; k < K; ++k) {
    _Float16 h = (_Float16)(edge_w[t * K + k] * rsp);
    hw[k] = __builtin_bit_cast(uint16_t, h);
  }
  r.w01 = (uint32_t)hw[0] | ((uint32_t)hw[1] << 16);
  r.w23 = (uint32_t)hw[2] | ((uint32_t)hw[3] << 16);
  r.w45 = (uint32_t)hw[4] | ((uint32_t)hw[5] << 16);
  r.w67 = (uint32_t)hw[6] | ((uint32_t)hw[7] << 16);
  uint32_t oid = (uint32_t)out_idx[t];
  r.outPh = oid * 64u + ((oid & 31u) << 1);
  r.bias = bias[t];
  r.pad0 = 0; r.pad1 = 0;
  recs[pos] = r;

  if (t <= ml) g_loff[t] = offs[t + 1];   // g_loff[i] = start of level i+1; g_loff[ml] = NN
  if (t == 0)  g_nlev[0] = ml;
}

// ---------------------------------------------------------------------------
// Eval: one block per 64 batch elements (lane = batch element). Node values in
// 128 KiB LDS (fp16), XOR-swizzled (0 bank conflicts, HW-verified). 16 waves
// (4/SIMD) split each level's nodes; records prefetched one iter ahead (SGPRs).
// Plain compiler-generated ds_read_u16 reads (R3/R7-proven); fp16x2 packing +
// v_dot2_f32_f16 replace the scalar cvt+fma chain.
// ---------------------------------------------------------------------------
__global__ __launch_bounds__(TPB, 4)
void eval_kernel(const float* __restrict__ inputs,
                 const int* __restrict__ output_idx,
                 const int* __restrict__ g_nlev,
                 const int* __restrict__ g_loff,
                 const Rec* __restrict__ recs,
                 float* __restrict__ out)
{
  __shared__ _Float16 vals[N_NODES * NB];   // 128 KiB
  __shared__ int      loffs[MAXL + 1];

  const uint32_t tid  = threadIdx.x;
  const uint32_t lane = tid & 63u;
  const uint32_t wave = tid >> 6;           // 0..15
  const int      base = blockIdx.x * NB;

  const int nlev = g_nlev[0];
  for (int i = (int)tid; i <= nlev; i += TPB) loffs[i] = g_loff[i];

  // Stage 64 rows x 256 input cols: thread -> (col = tid&255, c-group = tid>>8).
  // Coalesced global reads (256 consecutive threads per c), swizzled LDS writes.
  const uint32_t col = tid & 255u;
  const uint32_t cg  = tid >> 8;            // 0..3
  const uint32_t swz = col * 64u + ((col & 31u) << 1);
  for (uint32_t c = cg; c < NB; c += 4) {
    float v = inputs[(size_t)(base + c) * NUM_IN + col];
    vals[swz ^ c] = (_Float16)v;
  }
  __syncthreads();

  for (int l = 0; l < nlev; ++l) {
    const int beg = loffs[l], end = loffs[l + 1];
    int j = beg + (int)wave;
    if (j < end) {
      Rec rr = recs[__builtin_amdgcn_readfirstlane(j)];
      for (;;) {
        // Prefetch next record (wave-uniform addr -> SGPRs) before the math.
        const int jn = j + WPB;
        const bool has = jn < end;
        Rec rn;
        if (has) rn = recs[__builtin_amdgcn_readfirstlane(jn)];

        const _Float16 x0 = vals[rr.p[0] ^ lane];
        const _Float16 x1 = vals[rr.p[1] ^ lane];
        const _Float16 x2 = vals[rr.p[2] ^ lane];
        const _Float16 x3 = vals[rr.p[3] ^ lane];
        const _Float16 x4 = vals[rr.p[4] ^ lane];
        const _Float16 x5 = vals[rr.p[5] ^ lane];
        const _Float16 x6 = vals[rr.p[6] ^ lane];
        const _Float16 x7 = vals[rr.p[7] ^ lane];

        const h2 v01 = {x0, x1};
        const h2 v23 = {x2, x3};
        const h2 v45 = {x4, x5};
        const h2 v67 = {x6, x7};

#if __has_builtin(__builtin_amdgcn_fdot2)
        float x = rr.bias;
        x = __builtin_amdgcn_fdot2(v01, __builtin_bit_cast(h2, rr.w01), x, false);
        x = __builtin_amdgcn_fdot2(v23, __builtin_bit_cast(h2, rr.w23), x, false);
        x = __builtin_amdgcn_fdot2(v45, __builtin_bit_cast(h2, rr.w45), x, false);
        x = __builtin_amdgcn_fdot2(v67, __builtin_bit_cast(h2, rr.w67), x, false);
#else
        const h2 w01 = __builtin_bit_cast(h2, rr.w01);
        const h2 w23 = __builtin_bit_cast(h2, rr.w23);
        const h2 w45 = __builtin_bit_cast(h2, rr.w45);
        const h2 w67 = __builtin_bit_cast(h2, rr.w67);
        float s0 = __builtin_fmaf((float)w01.x, (float)v01.x, rr.bias);
        float s1 = (float)w01.y * (float)v01.y;
        float s2 = (float)w23.x * (float)v23.x;
        float s3 = (float)w23.y * (float)v23.y;
        s0 = __builtin_fmaf((float)w45.x, (float)v45.x, s0);
        s1 = __builtin_fmaf((float)w45.y, (float)v45.y, s1);
        s2 = __builtin_fmaf((float)w67.x, (float)v67.x, s2);
        s3 = __builtin_fmaf((float)w67.y, (float)v67.y, s3);
        float x = (s0 + s1) + (s2 + s3);
#endif

        // tanh(x) = 1 - 2/(exp(2x)+1); saturates correctly at +-inf.
        const float e  = __expf(x + x);
        const float rc = __builtin_amdgcn_rcpf(e + 1.0f);
        const float y  = __builtin_fmaf(-2.0f, rc, 1.0f);

        vals[rr.outPh ^ lane] = (_Float16)y;

        if (!has) break;
        rr = rn; j = jn;
      }
    }
    __syncthreads();
  }

  // Emit outputs: out[(base+b)*64 + lane] (coalesced 256B/wave stores).
  const uint32_t oid  = (uint32_t)output_idx[lane];
  const uint32_t oswz = oid * 64u + ((oid & 31u) << 1);
  for (uint32_t k = 0; k < 4; ++k) {
    const uint32_t b = wave + k * 16u;
    float v = (float)vals[oswz ^ b];
    out[(size_t)(base + b) * NUM_OUT + lane] = v;
  }
}

// ---------------------------------------------------------------------------
extern "C" void kernel_launch(void* const* d_in, const int* in_sizes, int n_in,
                              void* d_out, int out_size, void* d_ws, size_t ws_size,
                              hipStream_t stream)
{
  (void)in_sizes; (void)n_in; (void)out_size; (void)ws_size;

  const float* inputs     = (const float*)d_in[0];
  const float* edge_w     = (const float*)d_in[1];
  const float* bias       = (const float*)d_in[2];
  const float* response   = (const float*)d_in[3];
  const int*   in_idx     = (const int*)d_in[4];
  // d_in[5] = edge_mask: all-true for this graph (deg = min(K, node) = K since
  // every non-input node id >= 256 > K), so it is ignored.
  const int*   out_idx    = (const int*)d_in[6];
  const int*   output_idx = (const int*)d_in[7];
  float*       out        = (float*)d_out;

  char* ws = (char*)d_ws;
  int* g_nlev = (int*)ws;                 // 1 int
  int* g_loff = (int*)(ws + 256);         // up to 800 ints
  Rec* recs   = (Rec*)(ws + 8192);        // 768 * 64B = 48 KiB

  hipLaunchKernelGGL(setup_kernel, dim3(1), dim3(NN), 0, stream,
                     in_idx, edge_w, bias, response, out_idx,
                     g_nlev, g_loff, recs);
  hipLaunchKernelGGL(eval_kernel, dim3(B_TOT / NB), dim3(TPB), 0, stream,
                     inputs, output_idx, g_nlev, g_loff, recs, out);
}

// Round 13
// 126.086 us; speedup vs baseline: 1.3537x; 1.0174x over previous
//
#include <hip/hip_runtime.h>
#include <stdint.h>
#include <stddef.h>

#define B_TOT   16384
#define NUM_IN  256
#define N_NODES 1024
#define NN      768
#define K       8
#define NUM_OUT 64
#define NB      64      // batch elements per block (= lanes)
#define MAXL    800     // max levels we can represent (true max = 768)
#define TPB     1024    // eval threads per block (16 waves, 4/SIMD)
#define WPB     16      // waves per eval block

typedef _Float16 h2 __attribute__((ext_vector_type(2)));

// 64-byte schedule record, one per non-input node, sorted by dependency level.
// p[k] = swizzled LDS BYTE base for pred k: (id*64 + ((id&31)<<1))*2; lane's
// byte address is p[k] ^ (lane<<1)  (single v_xor in the hot loop; XOR
// commutes with the *2 shift since the low bit is 0 on both sides).
// Weights are fp16 pairs (response folded in) feeding v_dot2_f32_f16.
struct Rec {
  uint32_t p[8];                 // byte-swizzled pred bases
  uint32_t w01, w23, w45, w67;   // fp16x2 packed weights
  uint32_t outPh;                // byte-swizzled output base
  float    bias;
  uint32_t pad0, pad1;
};
static_assert(sizeof(Rec) == 64, "Rec must be 64B");

// ---------------------------------------------------------------------------
// Setup: exact dependency levels via Jacobi ping-pong Bellman-Ford (1 barrier
// per iter; convergence checked every 4th iter with the R3-proven 3-barrier
// flag protocol — no flag-slot reuse, pure Jacobi between checks; iterations
// past the fixed point are idempotent). Then counting-sort by level, emit recs.
// ---------------------------------------------------------------------------
__global__ __launch_bounds__(NN)
void setup_kernel(const int* __restrict__ in_idx,
                  const float* __restrict__ edge_w,
                  const float* __restrict__ bias,
                  const float* __restrict__ response,
                  const int* __restrict__ out_idx,
                  int* __restrict__ g_nlev,
                  int* __restrict__ g_loff,
                  Rec* __restrict__ recs)
{
  __shared__ int lvlA[N_NODES];
  __shared__ int lvlB[N_NODES];
  __shared__ int hist[MAXL];
  __shared__ int cnt[MAXL];
  __shared__ int offs[MAXL + 2];
  __shared__ int changed;
  __shared__ int maxlv;

  const int t = threadIdx.x;

  for (int i = t; i < N_NODES; i += NN) { lvlA[i] = 0; lvlB[i] = 0; }
  for (int i = t; i < MAXL; i += NN) { hist[i] = 0; cnt[i] = 0; }
  if (t == 0) maxlv = 0;

  int idxs[K];
#pragma unroll
  for (int k = 0; k < K; ++k)
    idxs[k] = in_idx[t * K + k];       // deg == K for all nodes (node id >= 256)
  __syncthreads();

  // Jacobi BF: nxt[n] = 1 + max(cur[preds]); inputs stay 0 in both buffers.
  // Within an iter: reads touch only cur, writes touch only nxt (owner-writes)
  // -> one barrier suffices. The `changed` flag uses the 3-barrier protocol
  // (reset between (1),(2); set between (2),(3); read after (3)) at check
  // iters only.
  int* cur = lvlA;
  int* nxt = lvlB;
  int L = 1;
  for (int it = 0; it < 800; ++it) {
    int nl = 0;
#pragma unroll
    for (int k = 0; k < K; ++k) {
      int l = cur[idxs[k]];
      nl = (l > nl) ? l : nl;
    }
    nl += 1;
    nxt[NUM_IN + t] = nl;
    L = nl;
    if ((it & 3) == 3) {
      __syncthreads();               // (1) nxt writes + cur reads done
      if (t == 0) changed = 0;
      __syncthreads();               // (2) changed=0 visible
      if (nl != cur[NUM_IN + t]) changed = 1;
      __syncthreads();               // (3) flag final
      if (changed == 0) break;       // uniform exit; L = converged level
    } else {
      __syncthreads();               // nxt visible before it becomes cur
    }
    int* tmp = cur; cur = nxt; nxt = tmp;
  }

  atomicAdd(&hist[L], 1);
  atomicMax(&maxlv, L);
  __syncthreads();
  const int ml = maxlv;
  if (t == 0) {
    offs[1] = 0;
    for (int l = 1; l <= ml; ++l) offs[l + 1] = offs[l] + hist[l];
  }
  __syncthreads();
  const int pos = offs[L] + atomicAdd(&cnt[L], 1);

  // Build the packed record (byte-swizzled bases).
  Rec r;
#pragma unroll
  for (int k = 0; k < K; ++k) {
    uint32_t id = (uint32_t)idxs[k];
    r.p[k] = (id * 64u + ((id & 31u) << 1)) << 1;
  }
  const float rsp = response[t];
  uint16_t hw[K];
#pragma unroll
  for (int k = 0; k < K; ++k) {
    _Float16 h = (_Float16)(edge_w[t * K + k] * rsp);
    hw[k] = __builtin_bit_cast(uint16_t, h);
  }
  r.w01 = (uint32_t)hw[0] | ((uint32_t)hw[1] << 16);
  r.w23 = (uint32_t)hw[2] | ((uint32_t)hw[3] << 16);
  r.w45 = (uint32_t)hw[4] | ((uint32_t)hw[5] << 16);
  r.w67 = (uint32_t)hw[6] | ((uint32_t)hw[7] << 16);
  uint32_t oid = (uint32_t)out_idx[t];
  r.outPh = (oid * 64u + ((oid & 31u) << 1)) << 1;
  r.bias = bias[t];
  r.pad0 = 0; r.pad1 = 0;
  recs[pos] = r;

  if (t <= ml) g_loff[t] = offs[t + 1];   // g_loff[i] = start of level i+1; g_loff[ml] = NN
  if (t == 0)  g_nlev[0] = ml;
}

// ---------------------------------------------------------------------------
// Eval: one block per 64 batch elements (lane = batch element). Node values in
// 128 KiB LDS (fp16), XOR-swizzled (0 bank conflicts, HW-verified). 16 waves
// (4/SIMD); records prefetched one iter ahead (SGPRs); LDS value reads
// software-pipelined one node ahead (named A/B buffers — safe because a
// node's preds are strictly lower-level, so prefetched reads never alias
// current-level writes). fdot2 + byte-swizzled addressing (1 v_xor per read).
// ---------------------------------------------------------------------------
__global__ __launch_bounds__(TPB, 4)
void eval_kernel(const float* __restrict__ inputs,
                 const int* __restrict__ output_idx,
                 const int* __restrict__ g_nlev,
                 const int* __restrict__ g_loff,
                 const Rec* __restrict__ recs,
                 float* __restrict__ out)
{
  __shared__ _Float16 vals[N_NODES * NB];   // 128 KiB
  __shared__ int      loffs[MAXL + 1];

  const uint32_t tid  = threadIdx.x;
  const uint32_t lane = tid & 63u;
  const uint32_t wave = tid >> 6;           // 0..15
  const int      base = blockIdx.x * NB;

  const char*  vbytes  = (const char*)vals;
  char*        vbytesw = (char*)vals;
  const uint32_t lane2 = lane << 1;

  const int nlev = g_nlev[0];
  for (int i = (int)tid; i <= nlev; i += TPB) loffs[i] = g_loff[i];

  // Stage 64 rows x 256 input cols: thread -> (col = tid&255, c-group = tid>>8).
  // Coalesced global reads (256 consecutive threads per c), swizzled LDS writes.
  const uint32_t col = tid & 255u;
  const uint32_t cg  = tid >> 8;            // 0..3
  const uint32_t swz = col * 64u + ((col & 31u) << 1);   // element index
  for (uint32_t c = cg; c < NB; c += 4) {
    float v = inputs[(size_t)(base + c) * NUM_IN + col];
    vals[swz ^ c] = (_Float16)v;
  }
  __syncthreads();

#define LOADV(r, x0,x1,x2,x3,x4,x5,x6,x7) do {                      \
    x0 = *(const _Float16*)(vbytes + ((r).p[0] ^ lane2));           \
    x1 = *(const _Float16*)(vbytes + ((r).p[1] ^ lane2));           \
    x2 = *(const _Float16*)(vbytes + ((r).p[2] ^ lane2));           \
    x3 = *(const _Float16*)(vbytes + ((r).p[3] ^ lane2));           \
    x4 = *(const _Float16*)(vbytes + ((r).p[4] ^ lane2));           \
    x5 = *(const _Float16*)(vbytes + ((r).p[5] ^ lane2));           \
    x6 = *(const _Float16*)(vbytes + ((r).p[6] ^ lane2));           \
    x7 = *(const _Float16*)(vbytes + ((r).p[7] ^ lane2));           \
  } while (0)

#if __has_builtin(__builtin_amdgcn_fdot2)
#define DOT8(r, x0,x1,x2,x3,x4,x5,x6,x7, xx) do {                                   \
    h2 v01 = {x0, x1}, v23 = {x2, x3}, v45 = {x4, x5}, v67 = {x6, x7};              \
    xx = (r).bias;                                                                  \
    xx = __builtin_amdgcn_fdot2(v01, __builtin_bit_cast(h2, (r).w01), xx, false);   \
    xx = __builtin_amdgcn_fdot2(v23, __builtin_bit_cast(h2, (r).w23), xx, false);   \
    xx = __builtin_amdgcn_fdot2(v45, __builtin_bit_cast(h2, (r).w45), xx, false);   \
    xx = __builtin_amdgcn_fdot2(v67, __builtin_bit_cast(h2, (r).w67), xx, false);   \
  } while (0)
#else
#define DOT8(r, x0,x1,x2,x3,x4,x5,x6,x7, xx) do {                                   \
    h2 w01 = __builtin_bit_cast(h2, (r).w01), w23 = __builtin_bit_cast(h2, (r).w23);\
    h2 w45 = __builtin_bit_cast(h2, (r).w45), w67 = __builtin_bit_cast(h2, (r).w67);\
    float s0 = __builtin_fmaf((float)w01.x, (float)x0, (r).bias);                   \
    float s1 = (float)w01.y * (float)x1;                                            \
    float s2 = (float)w23.x * (float)x2;                                            \
    float s3 = (float)w23.y * (float)x3;                                            \
    s0 = __builtin_fmaf((float)w45.x, (float)x4, s0);                               \
    s1 = __builtin_fmaf((float)w45.y, (float)x5, s1);                               \
    s2 = __builtin_fmaf((float)w67.x, (float)x6, s2);                               \
    s3 = __builtin_fmaf((float)w67.y, (float)x7, s3);                               \
    xx = (s0 + s1) + (s2 + s3);                                                     \
  } while (0)
#endif

#define COMPUTE(r, x0,x1,x2,x3,x4,x5,x6,x7) do {                    \
    float xx;                                                       \
    DOT8(r, x0,x1,x2,x3,x4,x5,x6,x7, xx);                           \
    const float e  = __expf(xx + xx);                               \
    const float rc = __builtin_amdgcn_rcpf(e + 1.0f);               \
    const float y  = __builtin_fmaf(-2.0f, rc, 1.0f);               \
    *(_Float16*)(vbytesw + ((r).outPh ^ lane2)) = (_Float16)y;      \
  } while (0)

  for (int l = 0; l < nlev; ++l) {
    const int beg = loffs[l], end = loffs[l + 1];
    int j = beg + (int)wave;
    if (j < end) {
      Rec rA = recs[__builtin_amdgcn_readfirstlane(j)];
      _Float16 a0, a1, a2, a3, a4, a5, a6, a7;
      LOADV(rA, a0, a1, a2, a3, a4, a5, a6, a7);
      for (;;) {
        int jn = j + WPB;
        if (jn >= end) { COMPUTE(rA, a0, a1, a2, a3, a4, a5, a6, a7); break; }
        Rec rB = recs[__builtin_amdgcn_readfirstlane(jn)];
        _Float16 b0, b1, b2, b3, b4, b5, b6, b7;
        LOADV(rB, b0, b1, b2, b3, b4, b5, b6, b7);
        COMPUTE(rA, a0, a1, a2, a3, a4, a5, a6, a7);
        j = jn; jn = j + WPB;
        if (jn >= end) { COMPUTE(rB, b0, b1, b2, b3, b4, b5, b6, b7); break; }
        rA = recs[__builtin_amdgcn_readfirstlane(jn)];
        LOADV(rA, a0, a1, a2, a3, a4, a5, a6, a7);
        COMPUTE(rB, b0, b1, b2, b3, b4, b5, b6, b7);
        j = jn;
      }
    }
    __syncthreads();
  }

  // Emit outputs: out[(base+b)*64 + lane] (coalesced 256B/wave stores).
  const uint32_t oid  = (uint32_t)output_idx[lane];
  const uint32_t oswz = oid * 64u + ((oid & 31u) << 1);   // element index
  for (uint32_t k = 0; k < 4; ++k) {
    const uint32_t b = wave + k * 16u;
    float v = (float)vals[oswz ^ b];
    out[(size_t)(base + b) * NUM_OUT + lane] = v;
  }
}

// ---------------------------------------------------------------------------
extern "C" void kernel_launch(void* const* d_in, const int* in_sizes, int n_in,
                              void* d_out, int out_size, void* d_ws, size_t ws_size,
                              hipStream_t stream)
{
  (void)in_sizes; (void)n_in; (void)out_size; (void)ws_size;

  const float* inputs     = (const float*)d_in[0];
  const float* edge_w     = (const float*)d_in[1];
  const float* bias       = (const float*)d_in[2];
  const float* response   = (const float*)d_in[3];
  const int*   in_idx     = (const int*)d_in[4];
  // d_in[5] = edge_mask: all-true for this graph (deg = min(K, node) = K since
  // every non-input node id >= 256 > K), so it is ignored.
  const int*   out_idx    = (const int*)d_in[6];
  const int*   output_idx = (const int*)d_in[7];
  float*       out        = (float*)d_out;

  char* ws = (char*)d_ws;
  int* g_nlev = (int*)ws;                 // 1 int
  int* g_loff = (int*)(ws + 256);         // up to 800 ints
  Rec* recs   = (Rec*)(ws + 8192);        // 768 * 64B = 48 KiB

  hipLaunchKernelGGL(setup_kernel, dim3(1), dim3(NN), 0, stream,
                     in_idx, edge_w, bias, response, out_idx,
                     g_nlev, g_loff, recs);
  hipLaunchKernelGGL(eval_kernel, dim3(B_TOT / NB), dim3(TPB), 0, stream,
                     inputs, output_idx, g_nlev, g_loff, recs, out);
}